// Round 13
// baseline (116.270 us; speedup 1.0000x reference)
//
#include <hip/hip_runtime.h>

#define BLK 512
#define MT 32            // mfma tile edge
#define IA 2             // A-frags per wave
#define IB 512           // rows per block = 8 waves * 32 * IA
#define TJQ 512          // q points per LDS chunk
#define SJ 8             // j-slices per b -> 32*8*2 = 512 blocks, one round

typedef __attribute__((ext_vector_type(8))) short short8;
typedef __attribute__((ext_vector_type(16))) float f32x16;

__device__ __forceinline__ unsigned int fmap(float f) {
  unsigned int b = __float_as_uint(f);
  return (b & 0x80000000u) ? ~b : (b | 0x80000000u);
}
__device__ __forceinline__ float funmap(unsigned int u) {
  return __uint_as_float((u & 0x80000000u) ? (u ^ 0x80000000u) : ~u);
}
__device__ __forceinline__ unsigned short f2bf(float f) {
  unsigned int u = __float_as_uint(f);
  u += 0x7FFFu + ((u >> 16) & 1u);
  return (unsigned short)(u >> 16);
}
__device__ __forceinline__ float bf2f(unsigned short h) {
  return __uint_as_float(((unsigned int)h) << 16);
}
__device__ __forceinline__ unsigned int pk(unsigned short a, unsigned short b) {
  return (unsigned int)a | ((unsigned int)b << 16);
}

union FragU { uint4 u; short8 s; };

// 4 MFMAs (2 A-frags x 2 B-frags) in one asm block, VGPR dests, single
// 18-cyc nop tail (covers D-write->VALU-read for the last MFMA; earlier
// ones have >=18 cyc of trailing MFMA issue on top). Validated hazard
// margin: R11/R12 ran 18 cyc after the FINAL mfma with absmax margin 0.
#define MFMA4(d0, d1, d2, d3, a0, a1, b0, b1, c)                        \
  asm("v_mfma_f32_32x32x16_bf16 %0, %4, %6, %8\n\t"                     \
      "v_mfma_f32_32x32x16_bf16 %1, %4, %7, %8\n\t"                     \
      "v_mfma_f32_32x32x16_bf16 %2, %5, %6, %8\n\t"                     \
      "v_mfma_f32_32x32x16_bf16 %3, %5, %7, %8\n\t"                     \
      "s_nop 7\n\t"                                                     \
      "s_nop 7\n\t"                                                     \
      "s_nop 1"                                                         \
      : "=&v"(d0), "=&v"(d1), "=&v"(d2), "=&v"(d3)                      \
      : "v"(a0), "v"(a1), "v"(b0), "v"(b1), "v"(c))

#define MIN3(acc, x, y)                                                 \
  asm("v_min3_f32 %0, %0, %1, %2" : "+v"(acc) : "v"(x), "v"(y))

// R13: compute the distance matrix ONCE, fold both chamfer directions.
// K-slot layout (16 slots, same-index A/B slots multiply):
//  A: [p2h xyz | p2l xyz | p2h xyz | p2l xyz | 1 1 | nph npl]
//  B: [ qh xyz |  qh xyz |  ql xyz |  ql xyz | nqh nqm | 1 1]
// => D = (p2h+p2l).(qh+ql) + |q|^2 + |p|^2 ~= |p-q|^2 (full distance).
// dist1: row-fold (run regs + lane shuffle epilogue) -> u1[b,i].
// dist2: col-fold (tree-min of 16 regs; d0&d2 / d1&d3 share columns) ->
//        LDS scmin via ds atomic umin on fmap'd values -> flush to u2[b,j].
__global__ __launch_bounds__(BLK, 2) void cl_mfma(
    const float* __restrict__ A, const float* __restrict__ Bp,
    unsigned int* __restrict__ umin, int N, int jslice, int Bn) {
  __shared__ uint4 sA[2][IB];        // 16 KB
  __shared__ uint4 sB[2][TJQ];       // 16 KB
  __shared__ unsigned int scmin[2048];  // 8 KB, col mins for this block's jslice

  const int b = blockIdx.z;
  const float* __restrict__ P = A;   // in_pc[b]  (rows)
  const float* __restrict__ Q = Bp;  // tgt_pc[b] (cols)
  unsigned int* __restrict__ u1 = umin + (size_t)b * N;
  unsigned int* __restrict__ u2 = umin + ((size_t)Bn + b) * N;

  const int t = threadIdx.x;
  const int ib0 = blockIdx.x * IB;
  const int jbase = blockIdx.y * jslice;
  const size_t boff = (size_t)b * 3 * N;
  const unsigned short one = 0x3F80u;  // bf16(1.0)

  // ---- init scmin + stage A-vectors ----
#pragma unroll
  for (int c = 0; c < 4; ++c) scmin[c * BLK + t] = 0xFFFFFFFFu;
  {
    int i = ib0 + t;
    float x = P[boff + i], y = P[boff + N + i], zz = P[boff + 2 * N + i];
    float ax = -2.f * x, ay = -2.f * y, az = -2.f * zz;
    unsigned short hx = f2bf(ax), hy = f2bf(ay), hz = f2bf(az);
    unsigned short lx = f2bf(ax - bf2f(hx)), ly = f2bf(ay - bf2f(hy)),
                   lz = f2bf(az - bf2f(hz));
    float np = fmaf(zz, zz, fmaf(y, y, x * x));
    unsigned short nph = f2bf(np);
    unsigned short npl = f2bf(np - bf2f(nph));
    sA[0][t] = make_uint4(pk(hx, hy), pk(hz, lx), pk(ly, lz), pk(hx, hy));
    sA[1][t] = make_uint4(pk(hz, lx), pk(ly, lz), pk(one, one), pk(nph, npl));
  }
  __syncthreads();

  const int w = t >> 6, l = t & 63, m = l & 31, g = l >> 5;
  FragU a0u, a1u;
  a0u.u = sA[g][w * (MT * IA) + m];        // rows w*64 + 0..31
  a1u.u = sA[g][w * (MT * IA) + MT + m];   // rows w*64 + 32..63
  const short8 af0 = a0u.s, af1 = a1u.s;

  float run0[16], run1[16];
  f32x16 zc;
#pragma unroll
  for (int r = 0; r < 16; ++r) { run0[r] = 3.0e38f; run1[r] = 3.0e38f; zc[r] = 0.0f; }

  const int nch = jslice / TJQ;  // 4
  float qx = Q[boff + jbase + t];
  float qy = Q[boff + N + jbase + t];
  float qz = Q[boff + 2 * N + jbase + t];

  for (int ch = 0; ch < nch; ++ch) {
    unsigned short hx = f2bf(qx), hy = f2bf(qy), hz = f2bf(qz);
    unsigned short lx = f2bf(qx - bf2f(hx)), ly = f2bf(qy - bf2f(hy)),
                   lz = f2bf(qz - bf2f(hz));
    float nq = fmaf(qz, qz, fmaf(qy, qy, qx * qx));
    unsigned short nqh = f2bf(nq);
    unsigned short nqm = f2bf(nq - bf2f(nqh));
    uint4 b0s = make_uint4(pk(hx, hy), pk(hz, hx), pk(hy, hz), pk(lx, ly));
    uint4 b1s = make_uint4(pk(lz, lx), pk(ly, lz), pk(nqh, nqm), pk(one, one));

    __syncthreads();  // previous chunk fully consumed
    sB[0][t] = b0s;
    sB[1][t] = b1s;
    {  // prefetch next chunk's q
      int jn = (ch + 1 < nch) ? (jbase + (ch + 1) * TJQ + t) : (jbase + t);
      qx = Q[boff + jn];
      qy = Q[boff + N + jn];
      qz = Q[boff + 2 * N + jn];
    }
    __syncthreads();

#pragma unroll
    for (int jt = 0; jt < TJQ / MT; jt += 2) {
      FragU ba, bb;
      ba.u = sB[g][(jt + 0) * MT + m];
      bb.u = sB[g][(jt + 1) * MT + m];
      f32x16 d0, d1, d2, d3;
      MFMA4(d0, d1, d2, d3, af0, af1, ba.s, bb.s, zc);
      // dist1: row-running mins
#pragma unroll
      for (int r = 0; r < 16; ++r) MIN3(run0[r], d0[r], d1[r]);
#pragma unroll
      for (int r = 0; r < 16; ++r) MIN3(run1[r], d2[r], d3[r]);
      // dist2: column mins. d0&d2 cover all 32 rows of col jt*32+m (this
      // wave's row range); d1&d3 likewise for col (jt+1)*32+m.
      float ca = fminf(d0[0], d2[0]);
      float cb = fminf(d1[0], d3[0]);
#pragma unroll
      for (int r = 1; r < 16; ++r) {
        ca = fminf(ca, fminf(d0[r], d2[r]));
        cb = fminf(cb, fminf(d1[r], d3[r]));
      }
      atomicMin(&scmin[ch * TJQ + (jt + 0) * MT + m], fmap(ca));
      atomicMin(&scmin[ch * TJQ + (jt + 1) * MT + m], fmap(cb));
    }
  }

  // ---- dist1 epilogue: min across 32 cols (lanes), atomicMin ----
  // C/D layout (m74/m101): col=lane&31, row=(reg&3)+8*(reg>>2)+4*(lane>>5)
#pragma unroll
  for (int r = 0; r < 16; ++r) {
    float v0 = run0[r], v1 = run1[r];
#pragma unroll
    for (int sh = 1; sh <= 16; sh <<= 1) {
      v0 = fminf(v0, __shfl_xor(v0, sh));
      v1 = fminf(v1, __shfl_xor(v1, sh));
    }
    if (m == 0) {
      int row = (r & 3) + 8 * (r >> 2) + 4 * g;
      int il0 = w * (MT * IA) + row;
      int il1 = il0 + MT;
      atomicMin(&u1[ib0 + il0], fmap(v0));
      atomicMin(&u1[ib0 + il1], fmap(v1));
    }
  }

  // ---- dist2 flush: scmin -> global ----
  __syncthreads();  // all waves' ds_min done
#pragma unroll
  for (int c = 0; c < 4; ++c) {
    int col = c * BLK + t;
    atomicMin(&u2[jbase + col], scmin[col]);
  }
}

// Parallel final reduce: u holds complete squared distances (256 KB).
__global__ __launch_bounds__(256) void cl_reduce(
    const unsigned int* __restrict__ u, float* __restrict__ out, int total) {
  const int t = threadIdx.x;
  const uint4* __restrict__ u4 = (const uint4*)u;
  const int n4 = total / 4;
  const int gid = blockIdx.x * 256 + t;
  const int gstride = gridDim.x * 256;
  double s = 0.0;
  for (int i = gid; i < n4; i += gstride) {
    uint4 v = u4[i];
    s += (double)funmap(v.x) + (double)funmap(v.y) +
         (double)funmap(v.z) + (double)funmap(v.w);
  }
  for (int off = 32; off > 0; off >>= 1) s += __shfl_down(s, off, 64);
  __shared__ double sw[4];
  if ((t & 63) == 0) sw[t >> 6] = s;
  __syncthreads();
  if (t == 0) {
    double tot = sw[0] + sw[1] + sw[2] + sw[3];
    atomicAdd(out, (float)(tot / (double)total));
  }
}

extern "C" void kernel_launch(void* const* d_in, const int* in_sizes, int n_in,
                              void* d_out, int out_size, void* d_ws, size_t ws_size,
                              hipStream_t stream) {
  const float* in_pc = (const float*)d_in[0];
  const float* tgt_pc = (const float*)d_in[1];
  const int B = 2, N = 16384;
  unsigned int* u = (unsigned int*)d_ws;  // [2][B][N] uints = 256 KB
  float* out = (float*)d_out;

  hipMemsetAsync(u, 0xFF, (size_t)2 * B * N * sizeof(unsigned int), stream);
  hipMemsetAsync(out, 0, sizeof(float), stream);

  const int jslice = N / SJ;             // 2048
  dim3 grid(N / IB, SJ, B);              // (32,8,2) = 512 blocks x 512 thr
  cl_mfma<<<grid, dim3(BLK), 0, stream>>>(in_pc, tgt_pc, u, N, jslice, B);

  const int total = 2 * B * N;
  cl_reduce<<<dim3(16), dim3(256), 0, stream>>>(u, out, total);
}

// Round 15
// 107.162 us; speedup vs baseline: 1.0850x; 1.0850x over previous
//
#include <hip/hip_runtime.h>

#define BLK 512
#define MT 32            // mfma tile edge
#define IA 2             // A-frags per wave
#define IB 512           // rows per block = 8 waves * 32 * IA
#define TJQ 512          // q points per LDS chunk
#define SJ 4             // j-slices per (dir,b) -> 512 blocks, one dispatch round

typedef __attribute__((ext_vector_type(8))) short short8;
typedef __attribute__((ext_vector_type(16))) float f32x16;

__device__ __forceinline__ unsigned int fmap(float f) {
  unsigned int b = __float_as_uint(f);
  return (b & 0x80000000u) ? ~b : (b | 0x80000000u);
}
__device__ __forceinline__ float funmap(unsigned int u) {
  return __uint_as_float((u & 0x80000000u) ? (u ^ 0x80000000u) : ~u);
}
__device__ __forceinline__ unsigned short f2bf(float f) {
  unsigned int u = __float_as_uint(f);
  u += 0x7FFFu + ((u >> 16) & 1u);
  return (unsigned short)(u >> 16);
}
__device__ __forceinline__ float bf2f(unsigned short h) {
  return __uint_as_float(((unsigned int)h) << 16);
}
__device__ __forceinline__ unsigned int pk(unsigned short a, unsigned short b) {
  return (unsigned int)a | ((unsigned int)b << 16);
}

union FragU { uint4 u; short8 s; };

// Two MFMAs into VGPR destinations ("=&v"), 18-cyc nop tail covers the
// D-write -> VALU-read hazard (validated R11/R12, absmax margin 0).
#define MFMA2(d0, d1, a, b0, b1, c)                                    \
  asm("v_mfma_f32_32x32x16_bf16 %0, %2, %3, %5\n\t"                    \
      "v_mfma_f32_32x32x16_bf16 %1, %2, %4, %5\n\t"                    \
      "s_nop 7\n\t"                                                    \
      "s_nop 7\n\t"                                                    \
      "s_nop 1"                                                        \
      : "=&v"(d0), "=&v"(d1)                                           \
      : "v"(a), "v"(b0), "v"(b1), "v"(c))

// All-VGPR min3 (R14's "+a" variant does NOT assemble on gfx950 --
// v_min3_f32 rejects AGPR operands).
#define MIN3(acc, x, y)                                                \
  asm("v_min3_f32 %0, %0, %1, %2" : "+v"(acc) : "v"(x), "v"(y))

// D_ij = |q_j|^2 - 2 p_i.q_j via split-bf16-compensated MFMA (k-slot layout
// verified R5-R13, absmax margin 0).
// R15: CHUNK-LOCAL accumulators. R11-R13 plateaued because run0/run1 are
// live across the high-pressure staging region, so the allocator AGPR-homes
// them and pays 2 copies per min3 (~20 us). cacc0/cacc1 live only inside the
// jt-loop (pressure ~104 VGPRs -> VGPR home), and merge into the long-lived
// run (AGPR, fine) once per chunk.
__global__ __launch_bounds__(BLK, 2) void cl_mfma(
    const float* __restrict__ A, const float* __restrict__ Bp,
    unsigned int* __restrict__ umin, int N, int jslice, int Bn) {
  __shared__ uint4 sA[2][IB];   // A-vec halves [g][row]
  __shared__ uint4 sB[2][TJQ];  // B-vec halves [g][point]
  __shared__ float sNP[IB];     // |p|^2 per row

  const int zi = blockIdx.z;
  const int dir = zi / Bn;
  const int b = zi - dir * Bn;
  const float* __restrict__ P = dir ? Bp : A;
  const float* __restrict__ Q = dir ? A : Bp;
  unsigned int* __restrict__ um = umin + ((size_t)dir * Bn + b) * N;

  const int t = threadIdx.x;
  const int ib0 = blockIdx.x * IB;
  const int jbase = blockIdx.y * jslice;
  const size_t boff = (size_t)b * 3 * N;
  const unsigned short one = 0x3F80u;  // bf16(1.0)

  // ---- stage A-vectors + |p|^2 (once) ----
  {
    int i = ib0 + t;
    float x = P[boff + i], y = P[boff + N + i], zz = P[boff + 2 * N + i];
    float ax = -2.f * x, ay = -2.f * y, az = -2.f * zz;
    unsigned short hx = f2bf(ax), hy = f2bf(ay), hz = f2bf(az);
    unsigned short lx = f2bf(ax - bf2f(hx)), ly = f2bf(ay - bf2f(hy)),
                   lz = f2bf(az - bf2f(hz));
    sA[0][t] = make_uint4(pk(hx, hy), pk(hz, lx), pk(ly, lz), pk(hx, hy));
    sA[1][t] = make_uint4(pk(hz, lx), pk(ly, lz), pk(one, one), pk(one, 0));
    sNP[t] = fmaf(zz, zz, fmaf(y, y, x * x));
  }
  __syncthreads();

  const int w = t >> 6, l = t & 63, m = l & 31, g = l >> 5;
  FragU a0u, a1u;
  a0u.u = sA[g][w * (MT * IA) + m];        // rows w*64 + 0..31
  a1u.u = sA[g][w * (MT * IA) + MT + m];   // rows w*64 + 32..63
  const short8 af0 = a0u.s, af1 = a1u.s;

  float run0[16], run1[16];
  f32x16 zc;
#pragma unroll
  for (int r = 0; r < 16; ++r) { run0[r] = 3.0e38f; run1[r] = 3.0e38f; zc[r] = 0.0f; }

  const int nch = jslice / TJQ;  // 8
  float qx = Q[boff + jbase + t];
  float qy = Q[boff + N + jbase + t];
  float qz = Q[boff + 2 * N + jbase + t];

  for (int ch = 0; ch < nch; ++ch) {
    unsigned short hx = f2bf(qx), hy = f2bf(qy), hz = f2bf(qz);
    unsigned short lx = f2bf(qx - bf2f(hx)), ly = f2bf(qy - bf2f(hy)),
                   lz = f2bf(qz - bf2f(hz));
    float nq = fmaf(qz, qz, fmaf(qy, qy, qx * qx));
    unsigned short nh = f2bf(nq);
    float r1 = nq - bf2f(nh);
    unsigned short nm = f2bf(r1);
    unsigned short nl = f2bf(r1 - bf2f(nm));
    uint4 b0s = make_uint4(pk(hx, hy), pk(hz, hx), pk(hy, hz), pk(lx, ly));
    uint4 b1s = make_uint4(pk(lz, lx), pk(ly, lz), pk(nh, nm), pk(nl, 0));

    __syncthreads();  // previous chunk fully consumed
    sB[0][t] = b0s;
    sB[1][t] = b1s;
    {  // prefetch next chunk's q
      int jn = (ch + 1 < nch) ? (jbase + (ch + 1) * TJQ + t) : (jbase + t);
      qx = Q[boff + jn];
      qy = Q[boff + N + jn];
      qz = Q[boff + 2 * N + jn];
    }
    __syncthreads();

    // chunk-local accumulators: born here, dead before next staging
    float cacc0[16], cacc1[16];
#pragma unroll
    for (int r = 0; r < 16; ++r) { cacc0[r] = 3.0e38f; cacc1[r] = 3.0e38f; }

#pragma unroll
    for (int jt = 0; jt < TJQ / MT; jt += 2) {
      FragU ba, bb;
      ba.u = sB[g][(jt + 0) * MT + m];
      bb.u = sB[g][(jt + 1) * MT + m];
      f32x16 d0, d1;
      MFMA2(d0, d1, af0, ba.s, bb.s, zc);
#pragma unroll
      for (int r = 0; r < 16; ++r) MIN3(cacc0[r], d0[r], d1[r]);
      f32x16 d2, d3;
      MFMA2(d2, d3, af1, ba.s, bb.s, zc);
#pragma unroll
      for (int r = 0; r < 16; ++r) MIN3(cacc1[r], d2[r], d3[r]);
    }

    // once-per-chunk merge into the long-lived (possibly AGPR-homed) run
#pragma unroll
    for (int r = 0; r < 16; ++r) {
      run0[r] = fminf(run0[r], cacc0[r]);
      run1[r] = fminf(run1[r], cacc1[r]);
    }
  }

  // ---- epilogue: min across 32 cols, add |p|^2, atomicMin ----
  // C/D layout (m74/m101): col=lane&31, row=(reg&3)+8*(reg>>2)+4*(lane>>5)
#pragma unroll
  for (int r = 0; r < 16; ++r) {
    float v0 = run0[r], v1 = run1[r];
#pragma unroll
    for (int sh = 1; sh <= 16; sh <<= 1) {
      v0 = fminf(v0, __shfl_xor(v0, sh));
      v1 = fminf(v1, __shfl_xor(v1, sh));
    }
    if (m == 0) {
      int row = (r & 3) + 8 * (r >> 2) + 4 * g;
      int il0 = w * (MT * IA) + row;
      int il1 = il0 + MT;
      atomicMin(&um[ib0 + il0], fmap(v0 + sNP[il0]));
      atomicMin(&um[ib0 + il1], fmap(v1 + sNP[il1]));
    }
  }
}

// Parallel final reduce: u holds complete squared distances (256 KB).
__global__ __launch_bounds__(256) void cl_reduce(
    const unsigned int* __restrict__ u, float* __restrict__ out, int total) {
  const int t = threadIdx.x;
  const uint4* __restrict__ u4 = (const uint4*)u;
  const int n4 = total / 4;
  const int gid = blockIdx.x * 256 + t;
  const int gstride = gridDim.x * 256;
  double s = 0.0;
  for (int i = gid; i < n4; i += gstride) {
    uint4 v = u4[i];
    s += (double)funmap(v.x) + (double)funmap(v.y) +
         (double)funmap(v.z) + (double)funmap(v.w);
  }
  for (int off = 32; off > 0; off >>= 1) s += __shfl_down(s, off, 64);
  __shared__ double sw[4];
  if ((t & 63) == 0) sw[t >> 6] = s;
  __syncthreads();
  if (t == 0) {
    double tot = sw[0] + sw[1] + sw[2] + sw[3];
    atomicAdd(out, (float)(tot / (double)total));
  }
}

extern "C" void kernel_launch(void* const* d_in, const int* in_sizes, int n_in,
                              void* d_out, int out_size, void* d_ws, size_t ws_size,
                              hipStream_t stream) {
  const float* in_pc = (const float*)d_in[0];
  const float* tgt_pc = (const float*)d_in[1];
  const int B = 2, N = 16384;
  unsigned int* u = (unsigned int*)d_ws;  // [2][B][N] uints = 256 KB
  float* out = (float*)d_out;

  hipMemsetAsync(u, 0xFF, (size_t)2 * B * N * sizeof(unsigned int), stream);
  hipMemsetAsync(out, 0, sizeof(float), stream);

  const int jslice = N / SJ;             // 4096
  dim3 grid(N / IB, SJ, 2 * B);          // (32,4,4) = 512 blocks x 512 thr
  cl_mfma<<<grid, dim3(BLK), 0, stream>>>(in_pc, tgt_pc, u, N, jslice, B);

  const int total = 2 * B * N;
  cl_reduce<<<dim3(16), dim3(256), 0, stream>>>(u, out, total);
}

// Round 16
// 101.029 us; speedup vs baseline: 1.1509x; 1.0607x over previous
//
#include <hip/hip_runtime.h>

#define BLK 256          // 4 waves
#define MT 32            // mfma tile edge
#define IA 2             // A-frags per wave
#define IB 256           // rows per block = 4 waves * 32 * IA
#define TJQ 512          // q points per LDS chunk
#define SJ 2             // j-slices per (dir,b) -> 64*2*4 = 512 blocks

typedef __attribute__((ext_vector_type(8))) short short8;
typedef __attribute__((ext_vector_type(16))) float f32x16;

__device__ __forceinline__ unsigned int fmap(float f) {
  unsigned int b = __float_as_uint(f);
  return (b & 0x80000000u) ? ~b : (b | 0x80000000u);
}
__device__ __forceinline__ float funmap(unsigned int u) {
  return __uint_as_float((u & 0x80000000u) ? (u ^ 0x80000000u) : ~u);
}
__device__ __forceinline__ unsigned short f2bf(float f) {
  unsigned int u = __float_as_uint(f);
  u += 0x7FFFu + ((u >> 16) & 1u);
  return (unsigned short)(u >> 16);
}
__device__ __forceinline__ float bf2f(unsigned short h) {
  return __uint_as_float(((unsigned int)h) << 16);
}
__device__ __forceinline__ unsigned int pk(unsigned short a, unsigned short b) {
  return (unsigned int)a | ((unsigned int)b << 16);
}

union FragU { uint4 u; short8 s; };

// Two MFMAs into VGPR destinations ("=&v"), 18-cyc nop tail covers the
// D-write -> VALU-read hazard (validated R11/R12, absmax margin 0).
#define MFMA2(d0, d1, a, b0, b1, c)                                    \
  asm("v_mfma_f32_32x32x16_bf16 %0, %2, %3, %5\n\t"                    \
      "v_mfma_f32_32x32x16_bf16 %1, %2, %4, %5\n\t"                    \
      "s_nop 7\n\t"                                                    \
      "s_nop 7\n\t"                                                    \
      "s_nop 1"                                                        \
      : "=&v"(d0), "=&v"(d1)                                           \
      : "v"(a), "v"(b0), "v"(b1), "v"(c))

// All-VGPR min3 (AGPR operands don't assemble for v_min3 on gfx950 -- R14).
#define MIN3(acc, x, y)                                                \
  asm("v_min3_f32 %0, %0, %1, %2" : "+v"(acc) : "v"(x), "v"(y))

// D_ij = |q_j|^2 - 2 p_i.q_j via split-bf16-compensated MFMA (k-slot layout
// verified R5-R15, absmax margin 0).
// R16: kill the AGPR-copy tax by BUDGET, not by constraint games.
// launch_bounds(256,2) -> 256-VGPR cap; live set ~110 fits with slack, so
// the allocator has no pressure motive to AGPR-home run0/run1 (the ~15-20us
// plateau mechanism of R11-R15). 512 blocks = 2/CU, one dispatch round.
__global__ __launch_bounds__(BLK, 2) void cl_mfma(
    const float* __restrict__ A, const float* __restrict__ Bp,
    unsigned int* __restrict__ umin, int N, int jslice, int Bn) {
  __shared__ uint4 sA[2][IB];   // 8 KB
  __shared__ uint4 sB[2][TJQ];  // 16 KB
  __shared__ float sNP[IB];     // 1 KB

  const int zi = blockIdx.z;
  const int dir = zi / Bn;
  const int b = zi - dir * Bn;
  const float* __restrict__ P = dir ? Bp : A;
  const float* __restrict__ Q = dir ? A : Bp;
  unsigned int* __restrict__ um = umin + ((size_t)dir * Bn + b) * N;

  const int t = threadIdx.x;
  const int ib0 = blockIdx.x * IB;
  const int jbase = blockIdx.y * jslice;
  const size_t boff = (size_t)b * 3 * N;
  const unsigned short one = 0x3F80u;  // bf16(1.0)

  // ---- stage A-vectors + |p|^2 (once; t covers all 256 rows) ----
  {
    int i = ib0 + t;
    float x = P[boff + i], y = P[boff + N + i], zz = P[boff + 2 * N + i];
    float ax = -2.f * x, ay = -2.f * y, az = -2.f * zz;
    unsigned short hx = f2bf(ax), hy = f2bf(ay), hz = f2bf(az);
    unsigned short lx = f2bf(ax - bf2f(hx)), ly = f2bf(ay - bf2f(hy)),
                   lz = f2bf(az - bf2f(hz));
    sA[0][t] = make_uint4(pk(hx, hy), pk(hz, lx), pk(ly, lz), pk(hx, hy));
    sA[1][t] = make_uint4(pk(hz, lx), pk(ly, lz), pk(one, one), pk(one, 0));
    sNP[t] = fmaf(zz, zz, fmaf(y, y, x * x));
  }
  __syncthreads();

  const int w = t >> 6, l = t & 63, m = l & 31, g = l >> 5;
  FragU a0u, a1u;
  a0u.u = sA[g][w * (MT * IA) + m];        // rows w*64 + 0..31
  a1u.u = sA[g][w * (MT * IA) + MT + m];   // rows w*64 + 32..63
  const short8 af0 = a0u.s, af1 = a1u.s;

  float run0[16], run1[16];
  f32x16 zc;
#pragma unroll
  for (int r = 0; r < 16; ++r) { run0[r] = 3.0e38f; run1[r] = 3.0e38f; zc[r] = 0.0f; }

  const int nch = jslice / TJQ;  // 16
  // prefetch chunk 0 (2 q points per thread)
  float qx0 = Q[boff + jbase + t];
  float qy0 = Q[boff + N + jbase + t];
  float qz0 = Q[boff + 2 * N + jbase + t];
  float qx1 = Q[boff + jbase + 256 + t];
  float qy1 = Q[boff + N + jbase + 256 + t];
  float qz1 = Q[boff + 2 * N + jbase + 256 + t];

  for (int ch = 0; ch < nch; ++ch) {
    uint4 b00, b01, b10, b11;
    {
      unsigned short hx = f2bf(qx0), hy = f2bf(qy0), hz = f2bf(qz0);
      unsigned short lx = f2bf(qx0 - bf2f(hx)), ly = f2bf(qy0 - bf2f(hy)),
                     lz = f2bf(qz0 - bf2f(hz));
      float nq = fmaf(qz0, qz0, fmaf(qy0, qy0, qx0 * qx0));
      unsigned short nh = f2bf(nq);
      float r1 = nq - bf2f(nh);
      unsigned short nm = f2bf(r1);
      unsigned short nl = f2bf(r1 - bf2f(nm));
      b00 = make_uint4(pk(hx, hy), pk(hz, hx), pk(hy, hz), pk(lx, ly));
      b01 = make_uint4(pk(lz, lx), pk(ly, lz), pk(nh, nm), pk(nl, 0));
    }
    {
      unsigned short hx = f2bf(qx1), hy = f2bf(qy1), hz = f2bf(qz1);
      unsigned short lx = f2bf(qx1 - bf2f(hx)), ly = f2bf(qy1 - bf2f(hy)),
                     lz = f2bf(qz1 - bf2f(hz));
      float nq = fmaf(qz1, qz1, fmaf(qy1, qy1, qx1 * qx1));
      unsigned short nh = f2bf(nq);
      float r1 = nq - bf2f(nh);
      unsigned short nm = f2bf(r1);
      unsigned short nl = f2bf(r1 - bf2f(nm));
      b10 = make_uint4(pk(hx, hy), pk(hz, hx), pk(hy, hz), pk(lx, ly));
      b11 = make_uint4(pk(lz, lx), pk(ly, lz), pk(nh, nm), pk(nl, 0));
    }

    __syncthreads();  // previous chunk fully consumed
    sB[0][t] = b00;
    sB[1][t] = b01;
    sB[0][256 + t] = b10;
    sB[1][256 + t] = b11;
    {  // prefetch next chunk's q
      int jn = (ch + 1 < nch) ? (jbase + (ch + 1) * TJQ + t) : (jbase + t);
      qx0 = Q[boff + jn];
      qy0 = Q[boff + N + jn];
      qz0 = Q[boff + 2 * N + jn];
      qx1 = Q[boff + jn + 256];
      qy1 = Q[boff + N + jn + 256];
      qz1 = Q[boff + 2 * N + jn + 256];
    }
    __syncthreads();

#pragma unroll
    for (int jt = 0; jt < TJQ / MT; jt += 2) {
      FragU ba, bb;
      ba.u = sB[g][(jt + 0) * MT + m];
      bb.u = sB[g][(jt + 1) * MT + m];
      f32x16 d0, d1;
      MFMA2(d0, d1, af0, ba.s, bb.s, zc);
#pragma unroll
      for (int r = 0; r < 16; ++r) MIN3(run0[r], d0[r], d1[r]);
      f32x16 d2, d3;
      MFMA2(d2, d3, af1, ba.s, bb.s, zc);
#pragma unroll
      for (int r = 0; r < 16; ++r) MIN3(run1[r], d2[r], d3[r]);
    }
  }

  // ---- epilogue: min across 32 cols, add |p|^2, atomicMin ----
  // C/D layout (m74/m101): col=lane&31, row=(reg&3)+8*(reg>>2)+4*(lane>>5)
#pragma unroll
  for (int r = 0; r < 16; ++r) {
    float v0 = run0[r], v1 = run1[r];
#pragma unroll
    for (int sh = 1; sh <= 16; sh <<= 1) {
      v0 = fminf(v0, __shfl_xor(v0, sh));
      v1 = fminf(v1, __shfl_xor(v1, sh));
    }
    if (m == 0) {
      int row = (r & 3) + 8 * (r >> 2) + 4 * g;
      int il0 = w * (MT * IA) + row;
      int il1 = il0 + MT;
      atomicMin(&um[ib0 + il0], fmap(v0 + sNP[il0]));
      atomicMin(&um[ib0 + il1], fmap(v1 + sNP[il1]));
    }
  }
}

// Parallel final reduce: u holds complete squared distances (256 KB).
__global__ __launch_bounds__(256) void cl_reduce(
    const unsigned int* __restrict__ u, float* __restrict__ out, int total) {
  const int t = threadIdx.x;
  const uint4* __restrict__ u4 = (const uint4*)u;
  const int n4 = total / 4;
  const int gid = blockIdx.x * 256 + t;
  const int gstride = gridDim.x * 256;
  double s = 0.0;
  for (int i = gid; i < n4; i += gstride) {
    uint4 v = u4[i];
    s += (double)funmap(v.x) + (double)funmap(v.y) +
         (double)funmap(v.z) + (double)funmap(v.w);
  }
  for (int off = 32; off > 0; off >>= 1) s += __shfl_down(s, off, 64);
  __shared__ double sw[4];
  if ((t & 63) == 0) sw[t >> 6] = s;
  __syncthreads();
  if (t == 0) {
    double tot = sw[0] + sw[1] + sw[2] + sw[3];
    atomicAdd(out, (float)(tot / (double)total));
  }
}

extern "C" void kernel_launch(void* const* d_in, const int* in_sizes, int n_in,
                              void* d_out, int out_size, void* d_ws, size_t ws_size,
                              hipStream_t stream) {
  const float* in_pc = (const float*)d_in[0];
  const float* tgt_pc = (const float*)d_in[1];
  const int B = 2, N = 16384;
  unsigned int* u = (unsigned int*)d_ws;  // [2][B][N] uints = 256 KB
  float* out = (float*)d_out;

  hipMemsetAsync(u, 0xFF, (size_t)2 * B * N * sizeof(unsigned int), stream);
  hipMemsetAsync(out, 0, sizeof(float), stream);

  const int jslice = N / SJ;             // 8192
  dim3 grid(N / IB, SJ, 2 * B);          // (64,2,4) = 512 blocks x 256 thr
  cl_mfma<<<grid, dim3(BLK), 0, stream>>>(in_pc, tgt_pc, u, N, jslice, B);

  const int total = 2 * B * N;
  cl_reduce<<<dim3(16), dim3(256), 0, stream>>>(u, out, total);
}